// Round 2
// baseline (66448.431 us; speedup 1.0000x reference)
//
#include <hip/hip_runtime.h>

typedef _Float16 f16;
typedef _Float16 half8 __attribute__((ext_vector_type(8)));
typedef float floatx4 __attribute__((ext_vector_type(4)));

#define HD 1024
#define HSZ (128*1024)   // one [128][1024] state buffer

// lds_red layout: [w2 (4)][col (32)][row (64) pad->72]
#define LRED(w2,col,row) ((w2)*2304 + (col)*72 + (row))

// ---------- math helpers ----------
__device__ __forceinline__ float sigf(float v){ return 1.0f/(1.0f + __expf(-v)); }
__device__ __forceinline__ float tanh_fast(float v){
  float a = fabsf(v);
  float e = __expf(-2.0f*a);
  float t = (1.0f - e)/(1.0f + e);
  return v < 0.0f ? -t : t;
}

// ---------- bypass (write-through) stores: no dirty L2 lines anywhere ----------
// sc0 sc1 = system-scope write-through to the memory-side coherence point.
// vmcnt retire == ack at coherence point -> cross-XCD visible without wbl2.
__device__ __forceinline__ void st_h16(const f16* p, float hn){
  unsigned v = (unsigned)__builtin_bit_cast(unsigned short, (f16)hn);
  asm volatile("global_store_short %0, %1, off sc0 sc1" :: "v"(p), "v"(v) : "memory");
}
__device__ __forceinline__ void st_f32(const float* p, float v){
  asm volatile("global_store_dword %0, %1, off sc0 sc1" :: "v"(p), "v"(v) : "memory");
}

// ---------- custom group barrier (2 independent groups of 128 blocks) ----------
// One-hop all-to-all: each block stores the target epoch into its OWN 64B slot,
// then 128 lanes (waves 0-1) each directly poll one peer's slot (exec-masked
// spin; lanes drop out as peers arrive). No aggregator, no epoch broadcast ->
// latency = last-arrival + one poll round.
// No release fence: all global stores in this kernel bypass L2 (sc0 sc1), and
// each wave drains vmcnt before the flag store, so data is at the coherence
// point before the flag. Acquire fence (L1/L2 invalidate) kept, per-wave, so
// every wave's subsequent cached h loads are ordered after its own invalidate.
#define BAR_FLAG_STRIDE 16            // 16 u32 = 64B per slot
// bar: flags 256*16 u32 (16 KB); zero 8192 u32

__device__ __forceinline__ void grpbar(unsigned* bar, unsigned target,
                                       int grp, int jb, int tid){
  asm volatile("s_waitcnt vmcnt(0)" ::: "memory");   // per-wave: bypass stores acked
  __syncthreads();
  if (tid < 128) {
    if (tid == 0)
      __hip_atomic_store(bar + (grp*128 + jb)*BAR_FLAG_STRIDE, target,
                         __ATOMIC_RELAXED, __HIP_MEMORY_SCOPE_AGENT);
    const unsigned* f = bar + (grp*128 + tid)*BAR_FLAG_STRIDE;
    while (__hip_atomic_load(f, __ATOMIC_RELAXED, __HIP_MEMORY_SCOPE_AGENT) < target)
      __builtin_amdgcn_s_sleep(1);
  }
  __syncthreads();
  __builtin_amdgcn_fence(__ATOMIC_ACQUIRE, "agent");  // per-wave L1/L2 inv
}

// ---------- prep kernels ----------
__global__ void permB(const float* __restrict__ S1, int K1,
                      const float* __restrict__ S2, int K2,
                      f16* __restrict__ dst, int KT, long total)
{
  long idx = (long)blockIdx.x*blockDim.x + threadIdx.x;
  if (idx >= total) return;
  int lane = idx & 63; long r1 = idx >> 6;
  int kt = (int)(r1 % KT); r1 /= KT;
  int nt = (int)(r1 & 1);  r1 >>= 1;
  int w  = (int)(r1 & 7);  int jb = (int)(r1 >> 3);
  int n = lane & 15, q = lane >> 4;
  int colidx = nt*16 + n;
  int g = colidx >> 3, dj = colidx & 7;
  int row = g*1024 + jb*8 + dj;
  int kbase = w*(KT*32) + kt*32 + q*8;
  f16* d = dst + (size_t)idx*8;
  #pragma unroll
  for (int i = 0; i < 8; ++i) {
    int k = kbase + i;
    float v = (k < K1) ? S1[(size_t)row*K1 + k] : S2[(size_t)row*K2 + (k - K1)];
    d[i] = (f16)v;
  }
}

// enc_Wih0 [4096][32] fp32 -> W0p[j][g][k] fp16 (j*128 + g*32 + k)
__global__ void permW0(const float* __restrict__ W, f16* __restrict__ dst){
  int idx = blockIdx.x*blockDim.x + threadIdx.x;
  if (idx >= 1024*128) return;
  int k = idx & 31, g = (idx >> 5) & 3, j = idx >> 7;
  dst[idx] = (f16)W[(size_t)(g*1024 + j)*32 + k];
}

__global__ void addvec(const float* __restrict__ a, const float* __restrict__ b,
                       float* __restrict__ o, int nel){
  int i = blockIdx.x*blockDim.x + threadIdx.x;
  if (i < nel) o[i] = a[i] + b[i];
}

__global__ void cvtf16(const float* __restrict__ a, f16* __restrict__ o, long nel){
  long i = (long)blockIdx.x*blockDim.x + threadIdx.x;
  if (i < nel) o[i] = (f16)a[i];
}

__global__ void zero_hc(f16* __restrict__ hb, unsigned* __restrict__ bar){
  long i = (long)blockIdx.x*blockDim.x + threadIdx.x;
  if (i < 3L*2*HSZ) hb[i] = (f16)0.f;
  if (i < 8192)     bar[i] = 0u;
}

// ---------- persistent kernel building blocks ----------
template<int KT>
__device__ __forceinline__ void loadB(half8* Bl, const f16* __restrict__ Bp,
                                      int jb, int w, int lane){
  const f16* src = Bp + ((size_t)(jb*8 + w))*(2*KT)*512 + (size_t)lane*8;
  #pragma unroll
  for (int f = 0; f < 2*KT; ++f)
    Bl[f] = *(const half8*)(src + (size_t)f*512);
}

// One [64 rows x 32 cols(8j x 4gates)] LSTM sub-step for this CU.
// c-state lives in a per-thread register (cross-interval thread mapping is
// stable: thread tid owns cell (r0 + tid>>3, j0 + (tid&7)) for each layer).
// XM: 0 none, 1 = encoder-l0 (x16[32]·W0p), 2 = decoder-l0 (xs scalar · w0c)
// PM: 1 = decoder-l2 (emit Wu partial dot products)
template<int KT, int XM, int PM>
__device__ __forceinline__ void run_unit(
    const half8* Bl,
    const f16* __restrict__ A1, const f16* __restrict__ A2,
    float& creg, f16* __restrict__ hout, const float* __restrict__ bl,
    const f16* __restrict__ x16r, const f16* __restrict__ W0pp, int t,
    const float* xsp, const float* __restrict__ w0cp,
    const float* __restrict__ Wup, float* __restrict__ partialp, int jb,
    float* lds_red, int r0, int j0, int w, int lane, int tid)
{
  const int n = lane & 15, q = lane >> 4;
  const int k0 = w * (KT*32);
  const f16* Aw = (KT == 8 && w >= 4) ? (A2 + (k0 - 1024)) : (A1 + k0);

  floatx4 acc[4][2] = {};
  #pragma unroll
  for (int kt = 0; kt < KT; ++kt) {
    half8 a[4];
    #pragma unroll
    for (int mt = 0; mt < 4; ++mt)
      a[mt] = *(const half8*)(Aw + (size_t)(r0 + mt*16 + n)*HD + (kt*32 + q*8));
    #pragma unroll
    for (int mt = 0; mt < 4; ++mt) {
      acc[mt][0] = __builtin_amdgcn_mfma_f32_16x16x32_f16(a[mt], Bl[kt],      acc[mt][0], 0, 0, 0);
      acc[mt][1] = __builtin_amdgcn_mfma_f32_16x16x32_f16(a[mt], Bl[KT + kt], acc[mt][1], 0, 0, 0);
    }
  }

  // 2-step cross-wave K reduction in LDS: waves 4-7 dump, waves 0-3 fold in.
  __syncthreads();
  if (w >= 4) {
    #pragma unroll
    for (int mt = 0; mt < 4; ++mt)
      #pragma unroll
      for (int nt = 0; nt < 2; ++nt) {
        int base = LRED(w-4, nt*16 + n, mt*16 + q*4);
        #pragma unroll
        for (int r = 0; r < 4; ++r) lds_red[base + r] = acc[mt][nt][r];
      }
  }
  __syncthreads();
  if (w < 4) {
    #pragma unroll
    for (int mt = 0; mt < 4; ++mt)
      #pragma unroll
      for (int nt = 0; nt < 2; ++nt) {
        int base = LRED(w, nt*16 + n, mt*16 + q*4);
        #pragma unroll
        for (int r = 0; r < 4; ++r)
          lds_red[base + r] += acc[mt][nt][r];
      }
  }
  __syncthreads();

  // reduce 4 partials + elementwise; thread = (row, dj)
  const int rrow = tid >> 3, rdj = tid & 7;
  const int rg = r0 + rrow;
  const int j  = j0 + rdj;
  float g4[4];
  #pragma unroll
  for (int gi = 0; gi < 4; ++gi) {
    const int col = gi*8 + rdj;
    float s = bl[gi*1024 + j];
    #pragma unroll
    for (int w2 = 0; w2 < 4; ++w2) s += lds_red[LRED(w2, col, rrow)];
    g4[gi] = s;
  }
  if (XM == 1) {
    const f16* xr = x16r + ((size_t)rg*512 + t)*32;
    const f16* wj = W0pp + (size_t)j*128;
    #pragma unroll
    for (int k = 0; k < 32; ++k) {
      float xk = (float)xr[k];
      g4[0] += xk * (float)wj[k];
      g4[1] += xk * (float)wj[32+k];
      g4[2] += xk * (float)wj[64+k];
      g4[3] += xk * (float)wj[96+k];
    }
  }
  if (XM == 2) {
    float xv = xsp[rrow];
    g4[0] += xv * w0cp[j];       g4[1] += xv * w0cp[1024+j];
    g4[2] += xv * w0cp[2048+j];  g4[3] += xv * w0cp[3072+j];
  }
  float iv = sigf(g4[0]), fv = sigf(g4[1]);
  float gv = tanh_fast(g4[2]), ov = sigf(g4[3]);
  float cn = fv*creg + iv*gv;
  creg = cn;
  float hn = ov * tanh_fast(cn);
  st_h16(hout + ((size_t)rg*HD + j), hn);
  if (PM == 1) {
    float pv = hn * Wup[j];
    pv += __shfl_xor(pv, 1); pv += __shfl_xor(pv, 2); pv += __shfl_xor(pv, 4);
    if ((lane & 7) == 0) st_f32(partialp + jb*128 + rg, pv);
  }
}

#define HB(l,pp)  (hbuf + ((size_t)((l)*2 + (pp)))*HSZ)

__global__ void __launch_bounds__(512)
__attribute__((amdgpu_waves_per_eu(2, 2)))
persist(
    const f16* __restrict__ Bp_e0, const f16* __restrict__ Bp_e1, const f16* __restrict__ Bp_e2,
    const f16* __restrict__ Bp_d0, const f16* __restrict__ Bp_d1, const f16* __restrict__ Bp_d2,
    const float* __restrict__ biases, const f16* __restrict__ x16, const f16* __restrict__ W0p,
    const float* __restrict__ w0c, const float* __restrict__ Wu, const float* __restrict__ bu_p,
    const float* __restrict__ y, const int* __restrict__ force,
    f16* __restrict__ hbuf,
    float* __restrict__ partial, float* __restrict__ dout,
    unsigned* __restrict__ bar)
{
  unsigned ep = 0;

  const int cu = blockIdx.x;
  const int mh = cu >> 7, jb = cu & 127;
  const int r0 = mh*64, j0 = jb*8;
  const int tid = threadIdx.x;
  const int w = tid >> 6, lane = tid & 63;

  __shared__ float lds_red[4*2304];   // 4 x [32 cols][72-pad rows] fp32 partials
  __shared__ float lds_x[512];
  __shared__ float xs[64];

  half8 B0[8], B1[16], B2[16];
  // c-state in registers: thread-private across the whole kernel; encoder
  // finals are exactly the decoder initials (same thread mapping).
  float c0 = 0.f, c1 = 0.f, c2 = 0.f;

  // ================= encoder =================
  loadB<4>(B0, Bp_e0, jb, w, lane);
  loadB<8>(B1, Bp_e1, jb, w, lane);
  loadB<8>(B2, Bp_e2, jb, w, lane);

  for (int s = 0; s < 514; ++s) {
    if (s < 512) {                 // layer 0, t = s  (x-term via VALU, XM=1)
      int t = s, p = t & 1;
      run_unit<4,1,0>(B0, HB(0,1-p), nullptr, c0, HB(0,p), biases,
                      x16, W0p, t, nullptr, nullptr, nullptr, nullptr, 0,
                      lds_red, r0, j0, w, lane, tid);
    }
    {                              // layer 1, t = s-1
      int t = s - 1;
      if (t >= 0 && t < 512) {
        int p = t & 1;
        run_unit<8,0,0>(B1, HB(0,p), HB(1,1-p), c1, HB(1,p), biases + 4096,
                        nullptr, nullptr, 0, nullptr, nullptr, nullptr, nullptr, 0,
                        lds_red, r0, j0, w, lane, tid);
      }
    }
    {                              // layer 2, t = s-2
      int t = s - 2;
      if (t >= 0 && t < 512) {
        int p = t & 1;
        run_unit<8,0,0>(B2, HB(1,p), HB(2,1-p), c2, HB(2,p), biases + 2*4096,
                        nullptr, nullptr, 0, nullptr, nullptr, nullptr, nullptr, 0,
                        lds_red, r0, j0, w, lane, tid);
      }
    }
    grpbar(bar, ++ep, mh, jb, tid);
  }

  // ================= decoder =================
  loadB<4>(B0, Bp_d0, jb, w, lane);
  loadB<8>(B1, Bp_d1, jb, w, lane);
  loadB<8>(B2, Bp_d2, jb, w, lane);

  for (int t = 0; t < 511; ++t) {
    const int p = t & 1;
    // ---- x / output pre-phase ----
    if (t > 0) {
      int seg = tid >> 6, rowx = tid & 63;
      float s = 0.f;
      const float* pp = partial + r0 + rowx;
      for (int jj = seg*16; jj < seg*16 + 16; ++jj) s += pp[jj*128];
      lds_x[seg*64 + rowx] = s;
    }
    __syncthreads();
    if (tid < 64) {
      float xv;
      if (t == 0) {
        if (jb == 0) st_f32(dout + (size_t)(r0+tid)*512, 0.0f);
        xv = y[(size_t)(r0+tid)*512];
      } else {
        float ov = bu_p[0];
        #pragma unroll
        for (int sg = 0; sg < 8; ++sg) ov += lds_x[sg*64 + tid];
        if (jb == 0) st_f32(dout + (size_t)(r0+tid)*512 + t, ov);
        xv = (force[t-1] > 0) ? y[(size_t)(r0+tid)*512 + t] : ov;
      }
      xs[tid] = xv;
    }
    // ---- layer 0 (scalar-x, XM=2) ----
    run_unit<4,2,0>(B0, HB(0,1-p), nullptr, c0, HB(0,p), biases + 3*4096,
                    nullptr, nullptr, 0, xs, w0c, nullptr, nullptr, 0,
                    lds_red, r0, j0, w, lane, tid);
    grpbar(bar, ++ep, mh, jb, tid);
    // ---- layer 1 ----
    run_unit<8,0,0>(B1, HB(0,p), HB(1,1-p), c1, HB(1,p), biases + 4*4096,
                    nullptr, nullptr, 0, nullptr, nullptr, nullptr, nullptr, 0,
                    lds_red, r0, j0, w, lane, tid);
    grpbar(bar, ++ep, mh, jb, tid);
    // ---- layer 2 (+ Wu partials, PM=1) ----
    run_unit<8,0,1>(B2, HB(1,p), HB(2,1-p), c2, HB(2,p), biases + 5*4096,
                    nullptr, nullptr, 0, nullptr, nullptr, Wu, partial, jb,
                    lds_red, r0, j0, w, lane, tid);
    grpbar(bar, ++ep, mh, jb, tid);
  }

  // ---- epilogue: out(510) -> dout[:,511] ----
  if (jb == 0 && tid < 64) {
    float ov = bu_p[0];
    for (int jj = 0; jj < 128; ++jj) ov += partial[jj*128 + r0 + tid];
    st_f32(dout + (size_t)(r0+tid)*512 + 511, ov);
  }
}

// ---------- host ----------
extern "C" void kernel_launch(void* const* d_in, const int* in_sizes, int n_in,
                              void* d_out, int out_size, void* d_ws, size_t ws_size,
                              hipStream_t stream)
{
  const float* x     = (const float*)d_in[0];
  const float* y     = (const float*)d_in[1];
  const int*   force = (const int*)  d_in[2];
  const float* eWih0 = (const float*)d_in[3];
  const float* eWhh0 = (const float*)d_in[4];
  const float* ebih0 = (const float*)d_in[5];
  const float* ebhh0 = (const float*)d_in[6];
  const float* eWih  = (const float*)d_in[7];
  const float* eWhh  = (const float*)d_in[8];
  const float* ebih  = (const float*)d_in[9];
  const float* ebhh  = (const float*)d_in[10];
  const float* dWih0 = (const float*)d_in[11];
  const float* dWhh0 = (const float*)d_in[12];
  const float* dbih0 = (const float*)d_in[13];
  const float* dbhh0 = (const float*)d_in[14];
  const float* dWih  = (const float*)d_in[15];
  const float* dWhh  = (const float*)d_in[16];
  const float* dbih  = (const float*)d_in[17];
  const float* dbhh  = (const float*)d_in[18];
  const float* Wu    = (const float*)d_in[19];
  const float* bu    = (const float*)d_in[20];
  float* out = (float*)d_out;

  char* ws = (char*)d_ws;
  size_t off = 0;
  auto alloc = [&](size_t bytes)->void* {
    void* pp = ws + off; off += (bytes + 255) & ~(size_t)255; return pp;
  };
  f16* Bp_e0 = (f16*)alloc(4096ULL*1024*2);
  f16* Bp_e1 = (f16*)alloc(4096ULL*2048*2);
  f16* Bp_e2 = (f16*)alloc(4096ULL*2048*2);
  f16* Bp_d0 = (f16*)alloc(4096ULL*1024*2);
  f16* Bp_d1 = (f16*)alloc(4096ULL*2048*2);
  f16* Bp_d2 = (f16*)alloc(4096ULL*2048*2);
  float* biases = (float*)alloc(6ULL*4096*4);
  f16* x16  = (f16*)alloc(128ULL*512*32*2);
  f16* W0p  = (f16*)alloc(1024ULL*128*2);
  f16* hbuf = (f16*)alloc(3ULL*2*HSZ*2);
  float* partialb = (float*)alloc(128ULL*128*4);
  unsigned* bar = (unsigned*)alloc(32*1024);   // flag slots (16KB used)
  (void)ws_size; (void)in_sizes; (void)n_in; (void)out_size;

  const int THR = 256;
  auto blocks = [&](long nel){ return dim3((unsigned)((nel + THR - 1)/THR)); };

  // --- prep: weight permutes ---
  long tot4 = 128L*8*2*4*64, tot8 = 128L*8*2*8*64;
  hipLaunchKernelGGL(permB, blocks(tot4), dim3(THR), 0, stream,
                     eWhh0, 1024, eWhh0, 1024, Bp_e0, 4, tot4);
  hipLaunchKernelGGL(permB, blocks(tot8), dim3(THR), 0, stream,
                     eWih, 1024, eWhh, 1024, Bp_e1, 8, tot8);
  hipLaunchKernelGGL(permB, blocks(tot8), dim3(THR), 0, stream,
                     eWih + 4096L*1024, 1024, eWhh + 4096L*1024, 1024, Bp_e2, 8, tot8);
  hipLaunchKernelGGL(permB, blocks(tot4), dim3(THR), 0, stream,
                     dWhh0, 1024, dWhh0, 1024, Bp_d0, 4, tot4);
  hipLaunchKernelGGL(permB, blocks(tot8), dim3(THR), 0, stream,
                     dWih, 1024, dWhh, 1024, Bp_d1, 8, tot8);
  hipLaunchKernelGGL(permB, blocks(tot8), dim3(THR), 0, stream,
                     dWih + 4096L*1024, 1024, dWhh + 4096L*1024, 1024, Bp_d2, 8, tot8);
  hipLaunchKernelGGL(permW0, blocks(1024L*128), dim3(THR), 0, stream, eWih0, W0p);

  hipLaunchKernelGGL(addvec, blocks(4096), dim3(THR), 0, stream, ebih0, ebhh0, biases + 0*4096, 4096);
  hipLaunchKernelGGL(addvec, blocks(4096), dim3(THR), 0, stream, ebih, ebhh, biases + 1*4096, 4096);
  hipLaunchKernelGGL(addvec, blocks(4096), dim3(THR), 0, stream, ebih + 4096, ebhh + 4096, biases + 2*4096, 4096);
  hipLaunchKernelGGL(addvec, blocks(4096), dim3(THR), 0, stream, dbih0, dbhh0, biases + 3*4096, 4096);
  hipLaunchKernelGGL(addvec, blocks(4096), dim3(THR), 0, stream, dbih, dbhh, biases + 4*4096, 4096);
  hipLaunchKernelGGL(addvec, blocks(4096), dim3(THR), 0, stream, dbih + 4096, dbhh + 4096, biases + 5*4096, 4096);

  hipLaunchKernelGGL(cvtf16, blocks(128L*512*32), dim3(THR), 0, stream, x, x16, 128L*512*32);
  hipLaunchKernelGGL(zero_hc, blocks(3L*2*HSZ), dim3(THR), 0, stream, hbuf, bar);

  // --- persistent cooperative kernel: encoder + decoder ---
  void* kargs[] = {
    (void*)&Bp_e0, (void*)&Bp_e1, (void*)&Bp_e2,
    (void*)&Bp_d0, (void*)&Bp_d1, (void*)&Bp_d2,
    (void*)&biases, (void*)&x16, (void*)&W0p,
    (void*)&dWih0, (void*)&Wu, (void*)&bu,
    (void*)&y, (void*)&force,
    (void*)&hbuf, (void*)&partialb, (void*)&out,
    (void*)&bar
  };
  hipLaunchCooperativeKernel((const void*)persist, dim3(256), dim3(512), kargs, 0, stream);
}

// Round 3
// 42437.250 us; speedup vs baseline: 1.5658x; 1.5658x over previous
//
#include <hip/hip_runtime.h>

typedef _Float16 f16;
typedef _Float16 half8 __attribute__((ext_vector_type(8)));
typedef float floatx4 __attribute__((ext_vector_type(4)));

#define HD 1024
#define HSZ (128*1024)   // one [128][1024] state buffer

// lds_red layout: [w2 (4)][col (32)][row (64) pad->72]
#define LRED(w2,col,row) ((w2)*2304 + (col)*72 + (row))

// ---------- math helpers ----------
__device__ __forceinline__ float sigf(float v){ return 1.0f/(1.0f + __expf(-v)); }
__device__ __forceinline__ float tanh_fast(float v){
  float a = fabsf(v);
  float e = __expf(-2.0f*a);
  float t = (1.0f - e)/(1.0f + e);
  return v < 0.0f ? -t : t;
}

// ---------- bypass (write-through) stores ----------
// sc0 sc1 = write-through to the memory-side coherence point; vmcnt retire ==
// ack there. ALL global stores in the persistent kernel use these, so the L2
// never holds a dirty persist line -> no release fence (buffer_wbl2) needed
// anywhere, and acquire invalidates operate on a clean L2 (no writeback walk).
__device__ __forceinline__ void st_h16(const f16* p, float hn){
  unsigned v = (unsigned)__builtin_bit_cast(unsigned short, (f16)hn);
  asm volatile("global_store_short %0, %1, off sc0 sc1" :: "v"(p), "v"(v) : "memory");
}
__device__ __forceinline__ void st_f32(const float* p, float v){
  asm volatile("global_store_dword %0, %1, off sc0 sc1" :: "v"(p), "v"(v) : "memory");
}

// ---------- custom group barrier (2 independent groups of 128 blocks) ----------
// Round-1-proven structure (58 ms context), minus the release fence:
//  Arrival: per-wave s_waitcnt vmcnt(0) (bypass stores acked at coherence
//  point) -> __syncthreads -> tid0 stores target epoch into its OWN 64B slot.
//  Aggregation: wave 0 of block jb==0 per group gathers all 128 flags with
//  lane-parallel agent-scope loads.
//  Release: epoch broadcast to 8 striped lines; <=16 pollers per line.
//  Acquire: ONE buffer_inv per block (tid0 only), before the closing
//  __syncthreads -- single invalidate per block avoids the round-2 regression
//  (8 staggered per-wave invs churned the L2 refill; FETCH_SIZE +1.4 GB).
#define BAR_FLAG_STRIDE 16            // 16 u32 = 64B per slot
#define BAR_EPOCH_OFF   4096          // u32 offset of epoch stripes
// bar: flags 256*16 u32 + epochs 16*16 u32 -> zero 8192 u32 (32 KB)

__device__ __forceinline__ void grpbar(unsigned* bar, unsigned target,
                                       int grp, int jb, int tid){
  asm volatile("s_waitcnt vmcnt(0)" ::: "memory");   // per-wave: stores acked
  __syncthreads();
  if (jb != 0) {
    if (tid == 0) {
      __hip_atomic_store(bar + (grp*128 + jb)*BAR_FLAG_STRIDE, target,
                         __ATOMIC_RELAXED, __HIP_MEMORY_SCOPE_AGENT);
      unsigned* ep = bar + BAR_EPOCH_OFF + (grp*8 + (jb & 7))*BAR_FLAG_STRIDE;
      while (__hip_atomic_load(ep, __ATOMIC_RELAXED, __HIP_MEMORY_SCOPE_AGENT) < target)
        __builtin_amdgcn_s_sleep(2);
      __builtin_amdgcn_fence(__ATOMIC_ACQUIRE, "agent");  // single L1/L2 inv
    }
  } else {
    // aggregator block: wave 0 only (threads 0..63)
    if (tid < 64) {
      unsigned* f1 = bar + (grp*128 + tid)*BAR_FLAG_STRIDE;
      unsigned* f2 = bar + (grp*128 + 64 + tid)*BAR_FLAG_STRIDE;
      for (;;) {
        unsigned a = (tid == 0) ? target
                   : __hip_atomic_load(f1, __ATOMIC_RELAXED, __HIP_MEMORY_SCOPE_AGENT);
        unsigned b = __hip_atomic_load(f2, __ATOMIC_RELAXED, __HIP_MEMORY_SCOPE_AGENT);
        if (__all(a >= target && b >= target)) break;
        __builtin_amdgcn_s_sleep(1);
      }
      if (tid < 8)
        __hip_atomic_store(bar + BAR_EPOCH_OFF + (grp*8 + tid)*BAR_FLAG_STRIDE, target,
                           __ATOMIC_RELAXED, __HIP_MEMORY_SCOPE_AGENT);
      if (tid == 0) __builtin_amdgcn_fence(__ATOMIC_ACQUIRE, "agent");
    }
  }
  __syncthreads();
}

// ---------- prep kernels ----------
__global__ void permB(const float* __restrict__ S1, int K1,
                      const float* __restrict__ S2, int K2,
                      f16* __restrict__ dst, int KT, long total)
{
  long idx = (long)blockIdx.x*blockDim.x + threadIdx.x;
  if (idx >= total) return;
  int lane = idx & 63; long r1 = idx >> 6;
  int kt = (int)(r1 % KT); r1 /= KT;
  int nt = (int)(r1 & 1);  r1 >>= 1;
  int w  = (int)(r1 & 7);  int jb = (int)(r1 >> 3);
  int n = lane & 15, q = lane >> 4;
  int colidx = nt*16 + n;
  int g = colidx >> 3, dj = colidx & 7;
  int row = g*1024 + jb*8 + dj;
  int kbase = w*(KT*32) + kt*32 + q*8;
  f16* d = dst + (size_t)idx*8;
  #pragma unroll
  for (int i = 0; i < 8; ++i) {
    int k = kbase + i;
    float v = (k < K1) ? S1[(size_t)row*K1 + k] : S2[(size_t)row*K2 + (k - K1)];
    d[i] = (f16)v;
  }
}

// enc_Wih0 [4096][32] fp32 -> W0p[j][g][k] fp16 (j*128 + g*32 + k)
__global__ void permW0(const float* __restrict__ W, f16* __restrict__ dst){
  int idx = blockIdx.x*blockDim.x + threadIdx.x;
  if (idx >= 1024*128) return;
  int k = idx & 31, g = (idx >> 5) & 3, j = idx >> 7;
  dst[idx] = (f16)W[(size_t)(g*1024 + j)*32 + k];
}

__global__ void addvec(const float* __restrict__ a, const float* __restrict__ b,
                       float* __restrict__ o, int nel){
  int i = blockIdx.x*blockDim.x + threadIdx.x;
  if (i < nel) o[i] = a[i] + b[i];
}

__global__ void cvtf16(const float* __restrict__ a, f16* __restrict__ o, long nel){
  long i = (long)blockIdx.x*blockDim.x + threadIdx.x;
  if (i < nel) o[i] = (f16)a[i];
}

__global__ void zero_hc(f16* __restrict__ hb, unsigned* __restrict__ bar){
  long i = (long)blockIdx.x*blockDim.x + threadIdx.x;
  if (i < 3L*2*HSZ) hb[i] = (f16)0.f;
  if (i < 8192)     bar[i] = 0u;
}

// ---------- persistent kernel building blocks ----------
template<int KT>
__device__ __forceinline__ void loadB(half8* Bl, const f16* __restrict__ Bp,
                                      int jb, int w, int lane){
  const f16* src = Bp + ((size_t)(jb*8 + w))*(2*KT)*512 + (size_t)lane*8;
  #pragma unroll
  for (int f = 0; f < 2*KT; ++f)
    Bl[f] = *(const half8*)(src + (size_t)f*512);
}

// One [64 rows x 32 cols(8j x 4gates)] LSTM sub-step for this CU.
// c-state lives in a per-thread register (stable thread<->cell mapping).
// XM: 0 none, 1 = encoder-l0 (x16[32]·W0p), 2 = decoder-l0 (xs scalar · w0c)
// PM: 1 = decoder-l2 (emit Wu partial dot products)
template<int KT, int XM, int PM>
__device__ __forceinline__ void run_unit(
    const half8* Bl,
    const f16* __restrict__ A1, const f16* __restrict__ A2,
    float& creg, f16* __restrict__ hout, const float* __restrict__ bl,
    const f16* __restrict__ x16r, const f16* __restrict__ W0pp, int t,
    const float* xsp, const float* __restrict__ w0cp,
    const float* __restrict__ Wup, float* __restrict__ partialp, int jb,
    float* lds_red, int r0, int j0, int w, int lane, int tid)
{
  const int n = lane & 15, q = lane >> 4;
  const int k0 = w * (KT*32);
  const f16* Aw = (KT == 8 && w >= 4) ? (A2 + (k0 - 1024)) : (A1 + k0);

  floatx4 acc[4][2] = {};
  #pragma unroll
  for (int kt = 0; kt < KT; ++kt) {
    half8 a[4];
    #pragma unroll
    for (int mt = 0; mt < 4; ++mt)
      a[mt] = *(const half8*)(Aw + (size_t)(r0 + mt*16 + n)*HD + (kt*32 + q*8));
    #pragma unroll
    for (int mt = 0; mt < 4; ++mt) {
      acc[mt][0] = __builtin_amdgcn_mfma_f32_16x16x32_f16(a[mt], Bl[kt],      acc[mt][0], 0, 0, 0);
      acc[mt][1] = __builtin_amdgcn_mfma_f32_16x16x32_f16(a[mt], Bl[KT + kt], acc[mt][1], 0, 0, 0);
    }
  }

  // 2-step cross-wave K reduction in LDS: waves 4-7 dump, waves 0-3 fold in.
  __syncthreads();
  if (w >= 4) {
    #pragma unroll
    for (int mt = 0; mt < 4; ++mt)
      #pragma unroll
      for (int nt = 0; nt < 2; ++nt) {
        int base = LRED(w-4, nt*16 + n, mt*16 + q*4);
        #pragma unroll
        for (int r = 0; r < 4; ++r) lds_red[base + r] = acc[mt][nt][r];
      }
  }
  __syncthreads();
  if (w < 4) {
    #pragma unroll
    for (int mt = 0; mt < 4; ++mt)
      #pragma unroll
      for (int nt = 0; nt < 2; ++nt) {
        int base = LRED(w, nt*16 + n, mt*16 + q*4);
        #pragma unroll
        for (int r = 0; r < 4; ++r)
          lds_red[base + r] += acc[mt][nt][r];
      }
  }
  __syncthreads();

  // reduce 4 partials + elementwise; thread = (row, dj)
  const int rrow = tid >> 3, rdj = tid & 7;
  const int rg = r0 + rrow;
  const int j  = j0 + rdj;
  float g4[4];
  #pragma unroll
  for (int gi = 0; gi < 4; ++gi) {
    const int col = gi*8 + rdj;
    float s = bl[gi*1024 + j];
    #pragma unroll
    for (int w2 = 0; w2 < 4; ++w2) s += lds_red[LRED(w2, col, rrow)];
    g4[gi] = s;
  }
  if (XM == 1) {
    const f16* xr = x16r + ((size_t)rg*512 + t)*32;
    const f16* wj = W0pp + (size_t)j*128;
    #pragma unroll
    for (int k = 0; k < 32; ++k) {
      float xk = (float)xr[k];
      g4[0] += xk * (float)wj[k];
      g4[1] += xk * (float)wj[32+k];
      g4[2] += xk * (float)wj[64+k];
      g4[3] += xk * (float)wj[96+k];
    }
  }
  if (XM == 2) {
    float xv = xsp[rrow];
    g4[0] += xv * w0cp[j];       g4[1] += xv * w0cp[1024+j];
    g4[2] += xv * w0cp[2048+j];  g4[3] += xv * w0cp[3072+j];
  }
  float iv = sigf(g4[0]), fv = sigf(g4[1]);
  float gv = tanh_fast(g4[2]), ov = sigf(g4[3]);
  float cn = fv*creg + iv*gv;
  creg = cn;
  float hn = ov * tanh_fast(cn);
  st_h16(hout + ((size_t)rg*HD + j), hn);
  if (PM == 1) {
    float pv = hn * Wup[j];
    pv += __shfl_xor(pv, 1); pv += __shfl_xor(pv, 2); pv += __shfl_xor(pv, 4);
    if ((lane & 7) == 0) st_f32(partialp + jb*128 + rg, pv);
  }
}

#define HB(l,pp)  (hbuf + ((size_t)((l)*2 + (pp)))*HSZ)

__global__ void __launch_bounds__(512)
__attribute__((amdgpu_waves_per_eu(2, 2)))
persist(
    const f16* __restrict__ Bp_e0, const f16* __restrict__ Bp_e1, const f16* __restrict__ Bp_e2,
    const f16* __restrict__ Bp_d0, const f16* __restrict__ Bp_d1, const f16* __restrict__ Bp_d2,
    const float* __restrict__ biases, const f16* __restrict__ x16, const f16* __restrict__ W0p,
    const float* __restrict__ w0c, const float* __restrict__ Wu, const float* __restrict__ bu_p,
    const float* __restrict__ y, const int* __restrict__ force,
    f16* __restrict__ hbuf,
    float* __restrict__ partial, float* __restrict__ dout,
    unsigned* __restrict__ bar)
{
  unsigned ep = 0;

  const int cu = blockIdx.x;
  const int mh = cu >> 7, jb = cu & 127;
  const int r0 = mh*64, j0 = jb*8;
  const int tid = threadIdx.x;
  const int w = tid >> 6, lane = tid & 63;

  __shared__ float lds_red[4*2304];   // 4 x [32 cols][72-pad rows] fp32 partials
  __shared__ float lds_x[512];
  __shared__ float xs[64];

  half8 B0[8], B1[16], B2[16];
  // c-state in registers: thread-private across the whole kernel; encoder
  // finals are exactly the decoder initials (same thread mapping).
  float c0 = 0.f, c1 = 0.f, c2 = 0.f;

  // ================= encoder =================
  loadB<4>(B0, Bp_e0, jb, w, lane);
  loadB<8>(B1, Bp_e1, jb, w, lane);
  loadB<8>(B2, Bp_e2, jb, w, lane);

  for (int s = 0; s < 514; ++s) {
    if (s < 512) {                 // layer 0, t = s  (x-term via VALU, XM=1)
      int t = s, p = t & 1;
      run_unit<4,1,0>(B0, HB(0,1-p), nullptr, c0, HB(0,p), biases,
                      x16, W0p, t, nullptr, nullptr, nullptr, nullptr, 0,
                      lds_red, r0, j0, w, lane, tid);
    }
    {                              // layer 1, t = s-1
      int t = s - 1;
      if (t >= 0 && t < 512) {
        int p = t & 1;
        run_unit<8,0,0>(B1, HB(0,p), HB(1,1-p), c1, HB(1,p), biases + 4096,
                        nullptr, nullptr, 0, nullptr, nullptr, nullptr, nullptr, 0,
                        lds_red, r0, j0, w, lane, tid);
      }
    }
    {                              // layer 2, t = s-2
      int t = s - 2;
      if (t >= 0 && t < 512) {
        int p = t & 1;
        run_unit<8,0,0>(B2, HB(1,p), HB(2,1-p), c2, HB(2,p), biases + 2*4096,
                        nullptr, nullptr, 0, nullptr, nullptr, nullptr, nullptr, 0,
                        lds_red, r0, j0, w, lane, tid);
      }
    }
    grpbar(bar, ++ep, mh, jb, tid);
  }

  // ================= decoder =================
  loadB<4>(B0, Bp_d0, jb, w, lane);
  loadB<8>(B1, Bp_d1, jb, w, lane);
  loadB<8>(B2, Bp_d2, jb, w, lane);

  for (int t = 0; t < 511; ++t) {
    const int p = t & 1;
    // ---- x / output pre-phase ----
    if (t > 0) {
      int seg = tid >> 6, rowx = tid & 63;
      float s = 0.f;
      const float* pp = partial + r0 + rowx;
      for (int jj = seg*16; jj < seg*16 + 16; ++jj) s += pp[jj*128];
      lds_x[seg*64 + rowx] = s;
    }
    __syncthreads();
    if (tid < 64) {
      float xv;
      if (t == 0) {
        if (jb == 0) st_f32(dout + (size_t)(r0+tid)*512, 0.0f);
        xv = y[(size_t)(r0+tid)*512];
      } else {
        float ov = bu_p[0];
        #pragma unroll
        for (int sg = 0; sg < 8; ++sg) ov += lds_x[sg*64 + tid];
        if (jb == 0) st_f32(dout + (size_t)(r0+tid)*512 + t, ov);
        xv = (force[t-1] > 0) ? y[(size_t)(r0+tid)*512 + t] : ov;
      }
      xs[tid] = xv;
    }
    // ---- layer 0 (scalar-x, XM=2) ----
    run_unit<4,2,0>(B0, HB(0,1-p), nullptr, c0, HB(0,p), biases + 3*4096,
                    nullptr, nullptr, 0, xs, w0c, nullptr, nullptr, 0,
                    lds_red, r0, j0, w, lane, tid);
    grpbar(bar, ++ep, mh, jb, tid);
    // ---- layer 1 ----
    run_unit<8,0,0>(B1, HB(0,p), HB(1,1-p), c1, HB(1,p), biases + 4*4096,
                    nullptr, nullptr, 0, nullptr, nullptr, nullptr, nullptr, 0,
                    lds_red, r0, j0, w, lane, tid);
    grpbar(bar, ++ep, mh, jb, tid);
    // ---- layer 2 (+ Wu partials, PM=1) ----
    run_unit<8,0,1>(B2, HB(1,p), HB(2,1-p), c2, HB(2,p), biases + 5*4096,
                    nullptr, nullptr, 0, nullptr, nullptr, Wu, partial, jb,
                    lds_red, r0, j0, w, lane, tid);
    grpbar(bar, ++ep, mh, jb, tid);
  }

  // ---- epilogue: out(510) -> dout[:,511] ----
  if (jb == 0 && tid < 64) {
    float ov = bu_p[0];
    for (int jj = 0; jj < 128; ++jj) ov += partial[jj*128 + r0 + tid];
    st_f32(dout + (size_t)(r0+tid)*512 + 511, ov);
  }
}

// ---------- host ----------
extern "C" void kernel_launch(void* const* d_in, const int* in_sizes, int n_in,
                              void* d_out, int out_size, void* d_ws, size_t ws_size,
                              hipStream_t stream)
{
  const float* x     = (const float*)d_in[0];
  const float* y     = (const float*)d_in[1];
  const int*   force = (const int*)  d_in[2];
  const float* eWih0 = (const float*)d_in[3];
  const float* eWhh0 = (const float*)d_in[4];
  const float* ebih0 = (const float*)d_in[5];
  const float* ebhh0 = (const float*)d_in[6];
  const float* eWih  = (const float*)d_in[7];
  const float* eWhh  = (const float*)d_in[8];
  const float* ebih  = (const float*)d_in[9];
  const float* ebhh  = (const float*)d_in[10];
  const float* dWih0 = (const float*)d_in[11];
  const float* dWhh0 = (const float*)d_in[12];
  const float* dbih0 = (const float*)d_in[13];
  const float* dbhh0 = (const float*)d_in[14];
  const float* dWih  = (const float*)d_in[15];
  const float* dWhh  = (const float*)d_in[16];
  const float* dbih  = (const float*)d_in[17];
  const float* dbhh  = (const float*)d_in[18];
  const float* Wu    = (const float*)d_in[19];
  const float* bu    = (const float*)d_in[20];
  float* out = (float*)d_out;

  char* ws = (char*)d_ws;
  size_t off = 0;
  auto alloc = [&](size_t bytes)->void* {
    void* pp = ws + off; off += (bytes + 255) & ~(size_t)255; return pp;
  };
  f16* Bp_e0 = (f16*)alloc(4096ULL*1024*2);
  f16* Bp_e1 = (f16*)alloc(4096ULL*2048*2);
  f16* Bp_e2 = (f16*)alloc(4096ULL*2048*2);
  f16* Bp_d0 = (f16*)alloc(4096ULL*1024*2);
  f16* Bp_d1 = (f16*)alloc(4096ULL*2048*2);
  f16* Bp_d2 = (f16*)alloc(4096ULL*2048*2);
  float* biases = (float*)alloc(6ULL*4096*4);
  f16* x16  = (f16*)alloc(128ULL*512*32*2);
  f16* W0p  = (f16*)alloc(1024ULL*128*2);
  f16* hbuf = (f16*)alloc(3ULL*2*HSZ*2);
  float* partialb = (float*)alloc(128ULL*128*4);
  unsigned* bar = (unsigned*)alloc(32*1024);   // flags + epoch stripes
  (void)ws_size; (void)in_sizes; (void)n_in; (void)out_size;

  const int THR = 256;
  auto blocks = [&](long nel){ return dim3((unsigned)((nel + THR - 1)/THR)); };

  // --- prep: weight permutes ---
  long tot4 = 128L*8*2*4*64, tot8 = 128L*8*2*8*64;
  hipLaunchKernelGGL(permB, blocks(tot4), dim3(THR), 0, stream,
                     eWhh0, 1024, eWhh0, 1024, Bp_e0, 4, tot4);
  hipLaunchKernelGGL(permB, blocks(tot8), dim3(THR), 0, stream,
                     eWih, 1024, eWhh, 1024, Bp_e1, 8, tot8);
  hipLaunchKernelGGL(permB, blocks(tot8), dim3(THR), 0, stream,
                     eWih + 4096L*1024, 1024, eWhh + 4096L*1024, 1024, Bp_e2, 8, tot8);
  hipLaunchKernelGGL(permB, blocks(tot4), dim3(THR), 0, stream,
                     dWhh0, 1024, dWhh0, 1024, Bp_d0, 4, tot4);
  hipLaunchKernelGGL(permB, blocks(tot8), dim3(THR), 0, stream,
                     dWih, 1024, dWhh, 1024, Bp_d1, 8, tot8);
  hipLaunchKernelGGL(permB, blocks(tot8), dim3(THR), 0, stream,
                     dWih + 4096L*1024, 1024, dWhh + 4096L*1024, 1024, Bp_d2, 8, tot8);
  hipLaunchKernelGGL(permW0, blocks(1024L*128), dim3(THR), 0, stream, eWih0, W0p);

  hipLaunchKernelGGL(addvec, blocks(4096), dim3(THR), 0, stream, ebih0, ebhh0, biases + 0*4096, 4096);
  hipLaunchKernelGGL(addvec, blocks(4096), dim3(THR), 0, stream, ebih, ebhh, biases + 1*4096, 4096);
  hipLaunchKernelGGL(addvec, blocks(4096), dim3(THR), 0, stream, ebih + 4096, ebhh + 4096, biases + 2*4096, 4096);
  hipLaunchKernelGGL(addvec, blocks(4096), dim3(THR), 0, stream, dbih0, dbhh0, biases + 3*4096, 4096);
  hipLaunchKernelGGL(addvec, blocks(4096), dim3(THR), 0, stream, dbih, dbhh, biases + 4*4096, 4096);
  hipLaunchKernelGGL(addvec, blocks(4096), dim3(THR), 0, stream, dbih + 4096, dbhh + 4096, biases + 5*4096, 4096);

  hipLaunchKernelGGL(cvtf16, blocks(128L*512*32), dim3(THR), 0, stream, x, x16, 128L*512*32);
  hipLaunchKernelGGL(zero_hc, blocks(3L*2*HSZ), dim3(THR), 0, stream, hbuf, bar);

  // --- persistent cooperative kernel: encoder + decoder ---
  void* kargs[] = {
    (void*)&Bp_e0, (void*)&Bp_e1, (void*)&Bp_e2,
    (void*)&Bp_d0, (void*)&Bp_d1, (void*)&Bp_d2,
    (void*)&biases, (void*)&x16, (void*)&W0p,
    (void*)&dWih0, (void*)&Wu, (void*)&bu,
    (void*)&y, (void*)&force,
    (void*)&hbuf, (void*)&partialb, (void*)&out,
    (void*)&bar
  };
  hipLaunchCooperativeKernel((const void*)persist, dim3(256), dim3(512), kargs, 0, stream);
}

// Round 5
// 39959.805 us; speedup vs baseline: 1.6629x; 1.0620x over previous
//
#include <hip/hip_runtime.h>

typedef _Float16 f16;
typedef _Float16 half8 __attribute__((ext_vector_type(8)));
typedef float floatx4 __attribute__((ext_vector_type(4)));

#define HD 1024
#define HSZ (128*1024)   // one [128][1024] state buffer

// lds_red layout: [w2 (4)][col (32)][row (64) pad->72]
#define LRED(w2,col,row) ((w2)*2304 + (col)*72 + (row))

// ---------- math helpers ----------
__device__ __forceinline__ float sigf(float v){ return 1.0f/(1.0f + __expf(-v)); }
__device__ __forceinline__ float tanh_fast(float v){
  float a = fabsf(v);
  float e = __expf(-2.0f*a);
  float t = (1.0f - e)/(1.0f + e);
  return v < 0.0f ? -t : t;
}

// ---------- bypass (write-through) stores ----------
// sc0 sc1 = write-through to the memory-side coherence point; vmcnt retire ==
// ack there. ALL persist-kernel global stores use these -> L2 never holds a
// dirty persist line -> no release fence (wbl2) needed anywhere, and acquire
// invalidates operate on a clean L2.
__device__ __forceinline__ void st_h16(const f16* p, float hn){
  unsigned v = (unsigned)__builtin_bit_cast(unsigned short, (f16)hn);
  asm volatile("global_store_short %0, %1, off sc0 sc1" :: "v"(p), "v"(v) : "memory");
}
__device__ __forceinline__ void st_f32(const float* p, float v){
  asm volatile("global_store_dword %0, %1, off sc0 sc1" :: "v"(p), "v"(v) : "memory");
}

// ---------- custom group barrier (2 independent groups of 128 blocks) ----------
// R3-proven structure (42.4 ms), with the acquire fence moved EARLY:
//  Arrival: per-wave s_waitcnt vmcnt(0) (bypass stores acked at coherence
//  point) -> __syncthreads -> tid0 stores target epoch into its OWN 64B slot.
//  EARLY acquire fence (vL1+L2 inv) runs BEFORE the spin, off the release
//  critical path. Sound because: (a) all waves of this block are parked until
//  the closing __syncthreads -> no cacheable loads between inv and release;
//  (b) the polls below are agent-scope (bypass L1/L2); (c) no co-resident
//  block can refill our h lines stale (same-group blocks are parked;
//  other-group blocks touch disjoint buffers; read-only data is immutable);
//  (d) MALL holds final h before any flag lands (write-through + vmcnt drain).
//  Aggregation: wave 0 of block jb==0 per group gathers all 128 flags with
//  lane-parallel agent-scope loads.
//  Release: epoch broadcast to 8 striped lines; <=16 pollers per line.
#define BAR_FLAG_STRIDE 16            // 16 u32 = 64B per slot
#define BAR_EPOCH_OFF   4096          // u32 offset of epoch stripes
// bar: flags 256*16 u32 + epochs 16*16 u32 -> zero 8192 u32 (32 KB)

__device__ __forceinline__ void grpbar(unsigned* bar, unsigned target,
                                       int grp, int jb, int tid){
  asm volatile("s_waitcnt vmcnt(0)" ::: "memory");   // per-wave: stores acked
  __syncthreads();
  if (jb != 0) {
    if (tid == 0) {
      __hip_atomic_store(bar + (grp*128 + jb)*BAR_FLAG_STRIDE, target,
                         __ATOMIC_RELAXED, __HIP_MEMORY_SCOPE_AGENT);
      __builtin_amdgcn_fence(__ATOMIC_ACQUIRE, "agent");   // EARLY inv (hidden)
      unsigned* ep = bar + BAR_EPOCH_OFF + (grp*8 + (jb & 7))*BAR_FLAG_STRIDE;
      while (__hip_atomic_load(ep, __ATOMIC_RELAXED, __HIP_MEMORY_SCOPE_AGENT) < target)
        __builtin_amdgcn_s_sleep(1);
    }
  } else {
    // aggregator block: wave 0 only (threads 0..63)
    if (tid < 64) {
      if (tid == 0) __builtin_amdgcn_fence(__ATOMIC_ACQUIRE, "agent"); // early
      unsigned* f1 = bar + (grp*128 + tid)*BAR_FLAG_STRIDE;
      unsigned* f2 = bar + (grp*128 + 64 + tid)*BAR_FLAG_STRIDE;
      for (;;) {
        unsigned a = (tid == 0) ? target
                   : __hip_atomic_load(f1, __ATOMIC_RELAXED, __HIP_MEMORY_SCOPE_AGENT);
        unsigned b = __hip_atomic_load(f2, __ATOMIC_RELAXED, __HIP_MEMORY_SCOPE_AGENT);
        if (__all(a >= target && b >= target)) break;
        __builtin_amdgcn_s_sleep(1);
      }
      if (tid < 8)
        __hip_atomic_store(bar + BAR_EPOCH_OFF + (grp*8 + tid)*BAR_FLAG_STRIDE, target,
                           __ATOMIC_RELAXED, __HIP_MEMORY_SCOPE_AGENT);
    }
  }
  __syncthreads();
}

// ---------- prep kernels ----------
__global__ void permB(const float* __restrict__ S1, int K1,
                      const float* __restrict__ S2, int K2,
                      f16* __restrict__ dst, int KT, long total)
{
  long idx = (long)blockIdx.x*blockDim.x + threadIdx.x;
  if (idx >= total) return;
  int lane = idx & 63; long r1 = idx >> 6;
  int kt = (int)(r1 % KT); r1 /= KT;
  int nt = (int)(r1 & 1);  r1 >>= 1;
  int w  = (int)(r1 & 7);  int jb = (int)(r1 >> 3);
  int n = lane & 15, q = lane >> 4;
  int colidx = nt*16 + n;
  int g = colidx >> 3, dj = colidx & 7;
  int row = g*1024 + jb*8 + dj;
  int kbase = w*(KT*32) + kt*32 + q*8;
  f16* d = dst + (size_t)idx*8;
  #pragma unroll
  for (int i = 0; i < 8; ++i) {
    int k = kbase + i;
    float v = (k < K1) ? S1[(size_t)row*K1 + k] : S2[(size_t)row*K2 + (k - K1)];
    d[i] = (f16)v;
  }
}

// enc_Wih0 [4096][32] fp32 -> W0p[j][g][k] fp16 (j*128 + g*32 + k)
__global__ void permW0(const float* __restrict__ W, f16* __restrict__ dst){
  int idx = blockIdx.x*blockDim.x + threadIdx.x;
  if (idx >= 1024*128) return;
  int k = idx & 31, g = (idx >> 5) & 3, j = idx >> 7;
  dst[idx] = (f16)W[(size_t)(g*1024 + j)*32 + k];
}

__global__ void addvec(const float* __restrict__ a, const float* __restrict__ b,
                       float* __restrict__ o, int nel){
  int i = blockIdx.x*blockDim.x + threadIdx.x;
  if (i < nel) o[i] = a[i] + b[i];
}

__global__ void cvtf16(const float* __restrict__ a, f16* __restrict__ o, long nel){
  long i = (long)blockIdx.x*blockDim.x + threadIdx.x;
  if (i < nel) o[i] = (f16)a[i];
}

__global__ void zero_hc(f16* __restrict__ hb, unsigned* __restrict__ bar){
  long i = (long)blockIdx.x*blockDim.x + threadIdx.x;
  if (i < 3L*2*HSZ) hb[i] = (f16)0.f;
  if (i < 8192)     bar[i] = 0u;
}

// ---------- persistent kernel building blocks ----------
template<int KT>
__device__ __forceinline__ void loadB(half8* Bl, const f16* __restrict__ Bp,
                                      int jb, int w, int lane){
  const f16* src = Bp + ((size_t)(jb*8 + w))*(2*KT)*512 + (size_t)lane*8;
  #pragma unroll
  for (int f = 0; f < 2*KT; ++f)
    Bl[f] = *(const half8*)(src + (size_t)f*512);
}

// One [64 rows x 32 cols(8j x 4gates)] LSTM sub-step for this CU.
// c-state lives in a per-thread register (stable thread<->cell mapping).
// XM: 0 none, 1 = encoder-l0 (x16[32]·W0p), 2 = decoder-l0 (xs scalar · w0c)
// PM: 1 = decoder-l2 (emit Wu partial dot products)
template<int KT, int XM, int PM>
__device__ __forceinline__ void run_unit(
    const half8* Bl,
    const f16* __restrict__ A1, const f16* __restrict__ A2,
    float& creg, f16* __restrict__ hout, const float* __restrict__ bl,
    const f16* __restrict__ x16r, const f16* __restrict__ W0pp, int t,
    const float* xsp, const float* __restrict__ w0cp,
    const float* __restrict__ Wup, float* __restrict__ partialp, int jb,
    float* lds_red, int r0, int j0, int w, int lane, int tid)
{
  const int n = lane & 15, q = lane >> 4;
  const int k0 = w * (KT*32);
  const f16* Aw = (KT == 8 && w >= 4) ? (A2 + (k0 - 1024)) : (A1 + k0);

  floatx4 acc[4][2] = {};
  #pragma unroll
  for (int kt = 0; kt < KT; ++kt) {
    half8 a[4];
    #pragma unroll
    for (int mt = 0; mt < 4; ++mt)
      a[mt] = *(const half8*)(Aw + (size_t)(r0 + mt*16 + n)*HD + (kt*32 + q*8));
    #pragma unroll
    for (int mt = 0; mt < 4; ++mt) {
      acc[mt][0] = __builtin_amdgcn_mfma_f32_16x16x32_f16(a[mt], Bl[kt],      acc[mt][0], 0, 0, 0);
      acc[mt][1] = __builtin_amdgcn_mfma_f32_16x16x32_f16(a[mt], Bl[KT + kt], acc[mt][1], 0, 0, 0);
    }
  }

  // 2-step cross-wave K reduction in LDS: waves 4-7 dump, waves 0-3 fold in.
  __syncthreads();
  if (w >= 4) {
    #pragma unroll
    for (int mt = 0; mt < 4; ++mt)
      #pragma unroll
      for (int nt = 0; nt < 2; ++nt) {
        int base = LRED(w-4, nt*16 + n, mt*16 + q*4);
        #pragma unroll
        for (int r = 0; r < 4; ++r) lds_red[base + r] = acc[mt][nt][r];
      }
  }
  __syncthreads();
  if (w < 4) {
    #pragma unroll
    for (int mt = 0; mt < 4; ++mt)
      #pragma unroll
      for (int nt = 0; nt < 2; ++nt) {
        int base = LRED(w, nt*16 + n, mt*16 + q*4);
        #pragma unroll
        for (int r = 0; r < 4; ++r)
          lds_red[base + r] += acc[mt][nt][r];
      }
  }
  __syncthreads();

  // reduce 4 partials + elementwise; thread = (row, dj)
  const int rrow = tid >> 3, rdj = tid & 7;
  const int rg = r0 + rrow;
  const int j  = j0 + rdj;
  float g4[4];
  #pragma unroll
  for (int gi = 0; gi < 4; ++gi) {
    const int col = gi*8 + rdj;
    float s = bl[gi*1024 + j];
    #pragma unroll
    for (int w2 = 0; w2 < 4; ++w2) s += lds_red[LRED(w2, col, rrow)];
    g4[gi] = s;
  }
  if (XM == 1) {
    const f16* xr = x16r + ((size_t)rg*512 + t)*32;
    const f16* wj = W0pp + (size_t)j*128;
    #pragma unroll
    for (int k = 0; k < 32; ++k) {
      float xk = (float)xr[k];
      g4[0] += xk * (float)wj[k];
      g4[1] += xk * (float)wj[32+k];
      g4[2] += xk * (float)wj[64+k];
      g4[3] += xk * (float)wj[96+k];
    }
  }
  if (XM == 2) {
    float xv = xsp[rrow];
    g4[0] += xv * w0cp[j];       g4[1] += xv * w0cp[1024+j];
    g4[2] += xv * w0cp[2048+j];  g4[3] += xv * w0cp[3072+j];
  }
  float iv = sigf(g4[0]), fv = sigf(g4[1]);
  float gv = tanh_fast(g4[2]), ov = sigf(g4[3]);
  float cn = fv*creg + iv*gv;
  creg = cn;
  float hn = ov * tanh_fast(cn);
  st_h16(hout + ((size_t)rg*HD + j), hn);
  if (PM == 1) {
    float pv = hn * Wup[j];
    pv += __shfl_xor(pv, 1); pv += __shfl_xor(pv, 2); pv += __shfl_xor(pv, 4);
    if ((lane & 7) == 0) st_f32(partialp + jb*128 + rg, pv);
  }
}

#define HB(l,pp)  (hbuf + ((size_t)((l)*2 + (pp)))*HSZ)

__global__ void __launch_bounds__(512)
__attribute__((amdgpu_waves_per_eu(2, 2)))
persist(
    const f16* __restrict__ Bp_e0, const f16* __restrict__ Bp_e1, const f16* __restrict__ Bp_e2,
    const f16* __restrict__ Bp_d0, const f16* __restrict__ Bp_d1, const f16* __restrict__ Bp_d2,
    const float* __restrict__ biases, const f16* __restrict__ x16, const f16* __restrict__ W0p,
    const float* __restrict__ w0c, const float* __restrict__ Wu, const float* __restrict__ bu_p,
    const float* __restrict__ y, const int* __restrict__ force,
    f16* __restrict__ hbuf,
    float* __restrict__ partial, float* __restrict__ dout,
    unsigned* __restrict__ bar)
{
  unsigned ep = 0;

  const int cu = blockIdx.x;
  // XCD-aligned group mapping: under round-robin dispatch (bid%8 = XCD) each
  // XCD holds blocks of ONE batch-half only -> per-XCD refetch set halves.
  // Bijective under ANY dispatch (perf heuristic only, never correctness).
  const int xgrp = cu & 7;
  const int mh = (xgrp >> 2) & 1;
  const int jb = (cu >> 3) * 4 + (xgrp & 3);
  const int r0 = mh*64, j0 = jb*8;
  const int tid = threadIdx.x;
  const int w = tid >> 6, lane = tid & 63;

  __shared__ float lds_red[4*2304];   // 4 x [32 cols][72-pad rows] fp32 partials
  __shared__ float lds_x[512];
  __shared__ float xs[64];

  half8 B0[8], B1[16], B2[16];
  // c-state in registers: thread-private across the whole kernel; encoder
  // finals are exactly the decoder initials (same thread mapping).
  float c0 = 0.f, c1 = 0.f, c2 = 0.f;

  // ================= encoder =================
  loadB<4>(B0, Bp_e0, jb, w, lane);
  loadB<8>(B1, Bp_e1, jb, w, lane);
  loadB<8>(B2, Bp_e2, jb, w, lane);

  for (int s = 0; s < 514; ++s) {
    if (s < 512) {                 // layer 0, t = s  (x-term via VALU, XM=1)
      int t = s, p = t & 1;
      run_unit<4,1,0>(B0, HB(0,1-p), nullptr, c0, HB(0,p), biases,
                      x16, W0p, t, nullptr, nullptr, nullptr, nullptr, 0,
                      lds_red, r0, j0, w, lane, tid);
    }
    {                              // layer 1, t = s-1
      int t = s - 1;
      if (t >= 0 && t < 512) {
        int p = t & 1;
        run_unit<8,0,0>(B1, HB(0,p), HB(1,1-p), c1, HB(1,p), biases + 4096,
                        nullptr, nullptr, 0, nullptr, nullptr, nullptr, nullptr, 0,
                        lds_red, r0, j0, w, lane, tid);
      }
    }
    {                              // layer 2, t = s-2
      int t = s - 2;
      if (t >= 0 && t < 512) {
        int p = t & 1;
        run_unit<8,0,0>(B2, HB(1,p), HB(2,1-p), c2, HB(2,p), biases + 2*4096,
                        nullptr, nullptr, 0, nullptr, nullptr, nullptr, nullptr, 0,
                        lds_red, r0, j0, w, lane, tid);
      }
    }
    grpbar(bar, ++ep, mh, jb, tid);
  }

  // ================= decoder =================
  loadB<4>(B0, Bp_d0, jb, w, lane);
  loadB<8>(B1, Bp_d1, jb, w, lane);
  loadB<8>(B2, Bp_d2, jb, w, lane);

  for (int t = 0; t < 511; ++t) {
    const int p = t & 1;
    // ---- x / output pre-phase ----
    if (t > 0) {
      int seg = tid >> 6, rowx = tid & 63;
      float s = 0.f;
      const float* pp = partial + r0 + rowx;
      for (int jj = seg*16; jj < seg*16 + 16; ++jj) s += pp[jj*128];
      lds_x[seg*64 + rowx] = s;
    }
    __syncthreads();
    if (tid < 64) {
      float xv;
      if (t == 0) {
        if (jb == 0) st_f32(dout + (size_t)(r0+tid)*512, 0.0f);
        xv = y[(size_t)(r0+tid)*512];
      } else {
        float ov = bu_p[0];
        #pragma unroll
        for (int sg = 0; sg < 8; ++sg) ov += lds_x[sg*64 + tid];
        if (jb == 0) st_f32(dout + (size_t)(r0+tid)*512 + t, ov);
        xv = (force[t-1] > 0) ? y[(size_t)(r0+tid)*512 + t] : ov;
      }
      xs[tid] = xv;
    }
    // ---- layer 0 (scalar-x, XM=2) ----
    run_unit<4,2,0>(B0, HB(0,1-p), nullptr, c0, HB(0,p), biases + 3*4096,
                    nullptr, nullptr, 0, xs, w0c, nullptr, nullptr, 0,
                    lds_red, r0, j0, w, lane, tid);
    grpbar(bar, ++ep, mh, jb, tid);
    // ---- layer 1 ----
    run_unit<8,0,0>(B1, HB(0,p), HB(1,1-p), c1, HB(1,p), biases + 4*4096,
                    nullptr, nullptr, 0, nullptr, nullptr, nullptr, nullptr, 0,
                    lds_red, r0, j0, w, lane, tid);
    grpbar(bar, ++ep, mh, jb, tid);
    // ---- layer 2 (+ Wu partials, PM=1) ----
    run_unit<8,0,1>(B2, HB(1,p), HB(2,1-p), c2, HB(2,p), biases + 5*4096,
                    nullptr, nullptr, 0, nullptr, nullptr, Wu, partial, jb,
                    lds_red, r0, j0, w, lane, tid);
    grpbar(bar, ++ep, mh, jb, tid);
  }

  // ---- epilogue: out(510) -> dout[:,511] ----
  if (jb == 0 && tid < 64) {
    float ov = bu_p[0];
    for (int jj = 0; jj < 128; ++jj) ov += partial[jj*128 + r0 + tid];
    st_f32(dout + (size_t)(r0+tid)*512 + 511, ov);
  }
}

// ---------- host ----------
extern "C" void kernel_launch(void* const* d_in, const int* in_sizes, int n_in,
                              void* d_out, int out_size, void* d_ws, size_t ws_size,
                              hipStream_t stream)
{
  const float* x     = (const float*)d_in[0];
  const float* y     = (const float*)d_in[1];
  const int*   force = (const int*)  d_in[2];
  const float* eWih0 = (const float*)d_in[3];
  const float* eWhh0 = (const float*)d_in[4];
  const float* ebih0 = (const float*)d_in[5];
  const float* ebhh0 = (const float*)d_in[6];
  const float* eWih  = (const float*)d_in[7];
  const float* eWhh  = (const float*)d_in[8];
  const float* ebih  = (const float*)d_in[9];
  const float* ebhh  = (const float*)d_in[10];
  const float* dWih0 = (const float*)d_in[11];
  const float* dWhh0 = (const float*)d_in[12];
  const float* dbih0 = (const float*)d_in[13];
  const float* dbhh0 = (const float*)d_in[14];
  const float* dWih  = (const float*)d_in[15];
  const float* dWhh  = (const float*)d_in[16];
  const float* dbih  = (const float*)d_in[17];
  const float* dbhh  = (const float*)d_in[18];
  const float* Wu    = (const float*)d_in[19];
  const float* bu    = (const float*)d_in[20];
  float* out = (float*)d_out;

  char* ws = (char*)d_ws;
  size_t off = 0;
  auto alloc = [&](size_t bytes)->void* {
    void* pp = ws + off; off += (bytes + 255) & ~(size_t)255; return pp;
  };
  f16* Bp_e0 = (f16*)alloc(4096ULL*1024*2);
  f16* Bp_e1 = (f16*)alloc(4096ULL*2048*2);
  f16* Bp_e2 = (f16*)alloc(4096ULL*2048*2);
  f16* Bp_d0 = (f16*)alloc(4096ULL*1024*2);
  f16* Bp_d1 = (f16*)alloc(4096ULL*2048*2);
  f16* Bp_d2 = (f16*)alloc(4096ULL*2048*2);
  float* biases = (float*)alloc(6ULL*4096*4);
  f16* x16  = (f16*)alloc(128ULL*512*32*2);
  f16* W0p  = (f16*)alloc(1024ULL*128*2);
  f16* hbuf = (f16*)alloc(3ULL*2*HSZ*2);
  float* partialb = (float*)alloc(128ULL*128*4);
  unsigned* bar = (unsigned*)alloc(32*1024);   // flags + epoch stripes
  (void)ws_size; (void)in_sizes; (void)n_in; (void)out_size;

  const int THR = 256;
  auto blocks = [&](long nel){ return dim3((unsigned)((nel + THR - 1)/THR)); };

  // --- prep: weight permutes ---
  long tot4 = 128L*8*2*4*64, tot8 = 128L*8*2*8*64;
  hipLaunchKernelGGL(permB, blocks(tot4), dim3(THR), 0, stream,
                     eWhh0, 1024, eWhh0, 1024, Bp_e0, 4, tot4);
  hipLaunchKernelGGL(permB, blocks(tot8), dim3(THR), 0, stream,
                     eWih, 1024, eWhh, 1024, Bp_e1, 8, tot8);
  hipLaunchKernelGGL(permB, blocks(tot8), dim3(THR), 0, stream,
                     eWih + 4096L*1024, 1024, eWhh + 4096L*1024, 1024, Bp_e2, 8, tot8);
  hipLaunchKernelGGL(permB, blocks(tot4), dim3(THR), 0, stream,
                     dWhh0, 1024, dWhh0, 1024, Bp_d0, 4, tot4);
  hipLaunchKernelGGL(permB, blocks(tot8), dim3(THR), 0, stream,
                     dWih, 1024, dWhh, 1024, Bp_d1, 8, tot8);
  hipLaunchKernelGGL(permB, blocks(tot8), dim3(THR), 0, stream,
                     dWih + 4096L*1024, 1024, dWhh + 4096L*1024, 1024, Bp_d2, 8, tot8);
  hipLaunchKernelGGL(permW0, blocks(1024L*128), dim3(THR), 0, stream, eWih0, W0p);

  hipLaunchKernelGGL(addvec, blocks(4096), dim3(THR), 0, stream, ebih0, ebhh0, biases + 0*4096, 4096);
  hipLaunchKernelGGL(addvec, blocks(4096), dim3(THR), 0, stream, ebih, ebhh, biases + 1*4096, 4096);
  hipLaunchKernelGGL(addvec, blocks(4096), dim3(THR), 0, stream, ebih + 4096, ebhh + 4096, biases + 2*4096, 4096);
  hipLaunchKernelGGL(addvec, blocks(4096), dim3(THR), 0, stream, dbih0, dbhh0, biases + 3*4096, 4096);
  hipLaunchKernelGGL(addvec, blocks(4096), dim3(THR), 0, stream, dbih, dbhh, biases + 4*4096, 4096);
  hipLaunchKernelGGL(addvec, blocks(4096), dim3(THR), 0, stream, dbih + 4096, dbhh + 4096, biases + 5*4096, 4096);

  hipLaunchKernelGGL(cvtf16, blocks(128L*512*32), dim3(THR), 0, stream, x, x16, 128L*512*32);
  hipLaunchKernelGGL(zero_hc, blocks(3L*2*HSZ), dim3(THR), 0, stream, hbuf, bar);

  // --- persistent cooperative kernel: encoder + decoder ---
  void* kargs[] = {
    (void*)&Bp_e0, (void*)&Bp_e1, (void*)&Bp_e2,
    (void*)&Bp_d0, (void*)&Bp_d1, (void*)&Bp_d2,
    (void*)&biases, (void*)&x16, (void*)&W0p,
    (void*)&dWih0, (void*)&Wu, (void*)&bu,
    (void*)&y, (void*)&force,
    (void*)&hbuf, (void*)&partialb, (void*)&out,
    (void*)&bar
  };
  hipLaunchCooperativeKernel((const void*)persist, dim3(256), dim3(512), kargs, 0, stream);
}

// Round 7
// 38352.313 us; speedup vs baseline: 1.7326x; 1.0419x over previous
//
#include <hip/hip_runtime.h>

typedef _Float16 f16;
typedef _Float16 half8 __attribute__((ext_vector_type(8)));
typedef float floatx4 __attribute__((ext_vector_type(4)));

#define HD 1024
#define HSZ (128*1024)   // one [128][1024] state buffer

// lds_red layout: [w2 (4)][col (32)][row (64) pad->72]
#define LRED(w2,col,row) ((w2)*2304 + (col)*72 + (row))

// ---------- math helpers ----------
__device__ __forceinline__ float sigf(float v){ return 1.0f/(1.0f + __expf(-v)); }
__device__ __forceinline__ float tanh_fast(float v){
  float a = fabsf(v);
  float e = __expf(-2.0f*a);
  float t = (1.0f - e)/(1.0f + e);
  return v < 0.0f ? -t : t;
}

// ---------- bypass (write-through) stores ----------
// sc0 sc1 = write-through to the memory-side coherence point; vmcnt retire ==
// ack there. ALL persist-kernel global stores use these -> L2 never holds a
// dirty persist line -> no release fence (wbl2) needed anywhere, and acquire
// invalidates operate on a clean L2.
__device__ __forceinline__ void st_h16(const f16* p, float hn){
  unsigned v = (unsigned)__builtin_bit_cast(unsigned short, (f16)hn);
  asm volatile("global_store_short %0, %1, off sc0 sc1" :: "v"(p), "v"(v) : "memory");
}
__device__ __forceinline__ void st_f32(const float* p, float v){
  asm volatile("global_store_dword %0, %1, off sc0 sc1" :: "v"(p), "v"(v) : "memory");
}

// ---------- custom group barrier (2 independent groups of 128 blocks) ----------
// R5-proven structure (39.96 ms), acquire fence AMORTIZED via h ring buffers:
// a ring slot is rewritten no sooner than 4 barriers (encoder) / 12 (decoder)
// after its previous use; an acquire fence (vL1+L2 inv) every 3rd barrier
// always falls between a line's last cached use and its next
// read-after-rewrite -> h reads are fresh, while 2/3 of barriers keep L1/L2
// warm (weights, biases, x16, A-tiles). Decoder alignment: dec eps %3 =
// (2,0,1) -> inv lands on the l2->x barrier, covering partial-reads and every
// h hand-off. Immutable data can never be stale; flags/epochs are agent-scope
// (bypass L1/L2); h stores are write-through (no dirty lines anywhere).
// DEFENSIVE: spins are bounded (2^20 polls) so a protocol bug produces a
// wrong-answer diagnostic instead of a container-killing hang.
#define BAR_FLAG_STRIDE 16            // 16 u32 = 64B per slot
#define BAR_EPOCH_OFF   4096          // u32 offset of epoch stripes
#define SPIN_CAP (1u<<20)
// bar: flags 256*16 u32 + epochs 16*16 u32 -> zero 8192 u32 (32 KB)

__device__ __forceinline__ void grpbar(unsigned* bar, unsigned target,
                                       int grp, int jb, int tid, bool doinv){
  asm volatile("s_waitcnt vmcnt(0)" ::: "memory");   // per-wave: stores acked
  __syncthreads();
  if (jb != 0) {
    if (tid == 0) {
      __hip_atomic_store(bar + (grp*128 + jb)*BAR_FLAG_STRIDE, target,
                         __ATOMIC_RELAXED, __HIP_MEMORY_SCOPE_AGENT);
      if (doinv)
        __builtin_amdgcn_fence(__ATOMIC_ACQUIRE, "agent");  // EARLY inv (hidden)
      unsigned* epp = bar + BAR_EPOCH_OFF + (grp*8 + (jb & 7))*BAR_FLAG_STRIDE;
      for (unsigned it = 0; it < SPIN_CAP; ++it) {
        if (__hip_atomic_load(epp, __ATOMIC_RELAXED, __HIP_MEMORY_SCOPE_AGENT) >= target)
          break;
        __builtin_amdgcn_s_sleep(1);
      }
    }
  } else {
    // aggregator block: wave 0 only (threads 0..63)
    if (tid < 64) {
      if (tid == 0 && doinv)
        __builtin_amdgcn_fence(__ATOMIC_ACQUIRE, "agent");  // early
      unsigned* f1 = bar + (grp*128 + tid)*BAR_FLAG_STRIDE;
      unsigned* f2 = bar + (grp*128 + 64 + tid)*BAR_FLAG_STRIDE;
      for (unsigned it = 0; it < SPIN_CAP; ++it) {
        unsigned a = (tid == 0) ? target
                   : __hip_atomic_load(f1, __ATOMIC_RELAXED, __HIP_MEMORY_SCOPE_AGENT);
        unsigned b = __hip_atomic_load(f2, __ATOMIC_RELAXED, __HIP_MEMORY_SCOPE_AGENT);
        if (__all(a >= target && b >= target)) break;
        __builtin_amdgcn_s_sleep(1);
      }
      if (tid < 8)
        __hip_atomic_store(bar + BAR_EPOCH_OFF + (grp*8 + tid)*BAR_FLAG_STRIDE, target,
                           __ATOMIC_RELAXED, __HIP_MEMORY_SCOPE_AGENT);
    }
  }
  __syncthreads();
}

// ---------- prep kernels ----------
__global__ void permB(const float* __restrict__ S1, int K1,
                      const float* __restrict__ S2, int K2,
                      f16* __restrict__ dst, int KT, long total)
{
  long idx = (long)blockIdx.x*blockDim.x + threadIdx.x;
  if (idx >= total) return;
  int lane = idx & 63; long r1 = idx >> 6;
  int kt = (int)(r1 % KT); r1 /= KT;
  int nt = (int)(r1 & 1);  r1 >>= 1;
  int w  = (int)(r1 & 7);  int jb = (int)(r1 >> 3);
  int n = lane & 15, q = lane >> 4;
  int colidx = nt*16 + n;
  int g = colidx >> 3, dj = colidx & 7;
  int row = g*1024 + jb*8 + dj;
  int kbase = w*(KT*32) + kt*32 + q*8;
  f16* d = dst + (size_t)idx*8;
  #pragma unroll
  for (int i = 0; i < 8; ++i) {
    int k = kbase + i;
    float v = (k < K1) ? S1[(size_t)row*K1 + k] : S2[(size_t)row*K2 + (k - K1)];
    d[i] = (f16)v;
  }
}

// enc_Wih0 [4096][32] fp32 -> W0p[j][g][k] fp16 (j*128 + g*32 + k)
__global__ void permW0(const float* __restrict__ W, f16* __restrict__ dst){
  int idx = blockIdx.x*blockDim.x + threadIdx.x;
  if (idx >= 1024*128) return;
  int k = idx & 31, g = (idx >> 5) & 3, j = idx >> 7;
  dst[idx] = (f16)W[(size_t)(g*1024 + j)*32 + k];
}

__global__ void addvec(const float* __restrict__ a, const float* __restrict__ b,
                       float* __restrict__ o, int nel){
  int i = blockIdx.x*blockDim.x + threadIdx.x;
  if (i < nel) o[i] = a[i] + b[i];
}

__global__ void cvtf16(const float* __restrict__ a, f16* __restrict__ o, long nel){
  long i = (long)blockIdx.x*blockDim.x + threadIdx.x;
  if (i < nel) o[i] = (f16)a[i];
}

__global__ void zero_hc(f16* __restrict__ hb, unsigned* __restrict__ bar){
  long i = (long)blockIdx.x*blockDim.x + threadIdx.x;
  if (i < 3L*4*HSZ) hb[i] = (f16)0.f;   // 3 layers x 4 ring slots
  if (i < 8192)     bar[i] = 0u;
}

// ---------- persistent kernel building blocks ----------
template<int KT>
__device__ __forceinline__ void loadB(half8* Bl, const f16* __restrict__ Bp,
                                      int jb, int w, int lane){
  const f16* src = Bp + ((size_t)(jb*8 + w))*(2*KT)*512 + (size_t)lane*8;
  #pragma unroll
  for (int f = 0; f < 2*KT; ++f)
    Bl[f] = *(const half8*)(src + (size_t)f*512);
}

// One [64 rows x 32 cols(8j x 4gates)] LSTM sub-step for this CU.
// c-state lives in a per-thread register (stable thread<->cell mapping).
// XM: 0 none, 1 = encoder-l0 (x16[32]·W0p), 2 = decoder-l0 (xs scalar · w0c)
// PM: 1 = decoder-l2 (emit Wu partial dot products)
template<int KT, int XM, int PM>
__device__ __forceinline__ void run_unit(
    const half8* Bl,
    const f16* __restrict__ A1, const f16* __restrict__ A2,
    float& creg, f16* __restrict__ hout, const float* __restrict__ bl,
    const f16* __restrict__ x16r, const f16* __restrict__ W0pp, int t,
    const float* xsp, const float* __restrict__ w0cp,
    const float* __restrict__ Wup, float* __restrict__ partialp, int jb,
    float* lds_red, int r0, int j0, int w, int lane, int tid)
{
  const int n = lane & 15, q = lane >> 4;
  const int k0 = w * (KT*32);
  const f16* Aw = (KT == 8 && w >= 4) ? (A2 + (k0 - 1024)) : (A1 + k0);

  floatx4 acc[4][2] = {};
  #pragma unroll
  for (int kt = 0; kt < KT; ++kt) {
    half8 a[4];
    #pragma unroll
    for (int mt = 0; mt < 4; ++mt)
      a[mt] = *(const half8*)(Aw + (size_t)(r0 + mt*16 + n)*HD + (kt*32 + q*8));
    #pragma unroll
    for (int mt = 0; mt < 4; ++mt) {
      acc[mt][0] = __builtin_amdgcn_mfma_f32_16x16x32_f16(a[mt], Bl[kt],      acc[mt][0], 0, 0, 0);
      acc[mt][1] = __builtin_amdgcn_mfma_f32_16x16x32_f16(a[mt], Bl[KT + kt], acc[mt][1], 0, 0, 0);
    }
  }

  // 2-step cross-wave K reduction in LDS: waves 4-7 dump, waves 0-3 fold in.
  __syncthreads();
  if (w >= 4) {
    #pragma unroll
    for (int mt = 0; mt < 4; ++mt)
      #pragma unroll
      for (int nt = 0; nt < 2; ++nt) {
        int base = LRED(w-4, nt*16 + n, mt*16 + q*4);
        #pragma unroll
        for (int r = 0; r < 4; ++r) lds_red[base + r] = acc[mt][nt][r];
      }
  }
  __syncthreads();
  if (w < 4) {
    #pragma unroll
    for (int mt = 0; mt < 4; ++mt)
      #pragma unroll
      for (int nt = 0; nt < 2; ++nt) {
        int base = LRED(w, nt*16 + n, mt*16 + q*4);
        #pragma unroll
        for (int r = 0; r < 4; ++r)
          lds_red[base + r] += acc[mt][nt][r];
      }
  }
  __syncthreads();

  // reduce 4 partials + elementwise; thread = (row, dj)
  const int rrow = tid >> 3, rdj = tid & 7;
  const int rg = r0 + rrow;
  const int j  = j0 + rdj;
  float g4[4];
  #pragma unroll
  for (int gi = 0; gi < 4; ++gi) {
    const int col = gi*8 + rdj;
    float s = bl[gi*1024 + j];
    #pragma unroll
    for (int w2 = 0; w2 < 4; ++w2) s += lds_red[LRED(w2, col, rrow)];
    g4[gi] = s;
  }
  if (XM == 1) {
    const f16* xr = x16r + ((size_t)rg*512 + t)*32;
    const f16* wj = W0pp + (size_t)j*128;
    #pragma unroll
    for (int k = 0; k < 32; ++k) {
      float xk = (float)xr[k];
      g4[0] += xk * (float)wj[k];
      g4[1] += xk * (float)wj[32+k];
      g4[2] += xk * (float)wj[64+k];
      g4[3] += xk * (float)wj[96+k];
    }
  }
  if (XM == 2) {
    float xv = xsp[rrow];
    g4[0] += xv * w0cp[j];       g4[1] += xv * w0cp[1024+j];
    g4[2] += xv * w0cp[2048+j];  g4[3] += xv * w0cp[3072+j];
  }
  float iv = sigf(g4[0]), fv = sigf(g4[1]);
  float gv = tanh_fast(g4[2]), ov = sigf(g4[3]);
  float cn = fv*creg + iv*gv;
  creg = cn;
  float hn = ov * tanh_fast(cn);
  st_h16(hout + ((size_t)rg*HD + j), hn);
  if (PM == 1) {
    float pv = hn * Wup[j];
    pv += __shfl_xor(pv, 1); pv += __shfl_xor(pv, 2); pv += __shfl_xor(pv, 4);
    if ((lane & 7) == 0) st_f32(partialp + jb*128 + rg, pv);
  }
}

// depth-4 ring per layer: HB(l, slot), slot in 0..3
#define HB(l,slot)  (hbuf + ((size_t)((l)*4 + (slot)))*HSZ)

__global__ void __launch_bounds__(512)
__attribute__((amdgpu_waves_per_eu(2, 2)))
persist(
    const f16* __restrict__ Bp_e0, const f16* __restrict__ Bp_e1, const f16* __restrict__ Bp_e2,
    const f16* __restrict__ Bp_d0, const f16* __restrict__ Bp_d1, const f16* __restrict__ Bp_d2,
    const float* __restrict__ biases, const f16* __restrict__ x16, const f16* __restrict__ W0p,
    const float* __restrict__ w0c, const float* __restrict__ Wu, const float* __restrict__ bu_p,
    const float* __restrict__ y, const int* __restrict__ force,
    f16* __restrict__ hbuf,
    float* __restrict__ partial, float* __restrict__ dout,
    unsigned* __restrict__ bar)
{
  unsigned ep = 0;

  const int cu = blockIdx.x;
  // XCD-aligned group mapping (R5-proven): under round-robin dispatch each
  // XCD holds blocks of ONE batch-half only. Bijective under ANY dispatch.
  const int xgrp = cu & 7;
  const int mh = (xgrp >> 2) & 1;
  const int jb = (cu >> 3) * 4 + (xgrp & 3);
  const int r0 = mh*64, j0 = jb*8;
  const int tid = threadIdx.x;
  const int w = tid >> 6, lane = tid & 63;

  __shared__ float lds_red[4*2304];   // 4 x [32 cols][72-pad rows] fp32 partials
  __shared__ float lds_x[512];
  __shared__ float xs[64];

  half8 B0[8], B1[16], B2[16];
  // c-state in registers: thread-private across the whole kernel; encoder
  // finals are exactly the decoder initials (same thread mapping).
  float c0 = 0.f, c1 = 0.f, c2 = 0.f;

  // ================= encoder =================
  loadB<4>(B0, Bp_e0, jb, w, lane);
  loadB<8>(B1, Bp_e1, jb, w, lane);
  loadB<8>(B2, Bp_e2, jb, w, lane);

  for (int s = 0; s < 514; ++s) {
    if (s < 512) {                 // layer 0, t = s  (x-term via VALU, XM=1)
      int t = s;
      run_unit<4,1,0>(B0, HB(0,(t+3)&3), nullptr, c0, HB(0,t&3), biases,
                      x16, W0p, t, nullptr, nullptr, nullptr, nullptr, 0,
                      lds_red, r0, j0, w, lane, tid);
    }
    {                              // layer 1, t = s-1
      int t = s - 1;
      if (t >= 0 && t < 512) {
        run_unit<8,0,0>(B1, HB(0,t&3), HB(1,(t+3)&3), c1, HB(1,t&3), biases + 4096,
                        nullptr, nullptr, 0, nullptr, nullptr, nullptr, nullptr, 0,
                        lds_red, r0, j0, w, lane, tid);
      }
    }
    {                              // layer 2, t = s-2
      int t = s - 2;
      if (t >= 0 && t < 512) {
        run_unit<8,0,0>(B2, HB(1,t&3), HB(2,(t+3)&3), c2, HB(2,t&3), biases + 2*4096,
                        nullptr, nullptr, 0, nullptr, nullptr, nullptr, nullptr, 0,
                        lds_red, r0, j0, w, lane, tid);
      }
    }
    ++ep;
    grpbar(bar, ep, mh, jb, tid, (ep % 3u) == 1u);
  }

  // ================= decoder =================
  // encoder finals: h_l(511) live in ring slot 511&3 = 3 == ((t=0)+3)&3.
  loadB<4>(B0, Bp_d0, jb, w, lane);
  loadB<8>(B1, Bp_d1, jb, w, lane);
  loadB<8>(B2, Bp_d2, jb, w, lane);

  for (int t = 0; t < 511; ++t) {
    // ---- x / output pre-phase ----
    if (t > 0) {
      int seg = tid >> 6, rowx = tid & 63;
      float s = 0.f;
      const float* pp = partial + r0 + rowx;
      for (int jj = seg*16; jj < seg*16 + 16; ++jj) s += pp[jj*128];
      lds_x[seg*64 + rowx] = s;
    }
    __syncthreads();
    if (tid < 64) {
      float xv;
      if (t == 0) {
        if (jb == 0) st_f32(dout + (size_t)(r0+tid)*512, 0.0f);
        xv = y[(size_t)(r0+tid)*512];
      } else {
        float ov = bu_p[0];
        #pragma unroll
        for (int sg = 0; sg < 8; ++sg) ov += lds_x[sg*64 + tid];
        if (jb == 0) st_f32(dout + (size_t)(r0+tid)*512 + t, ov);
        xv = (force[t-1] > 0) ? y[(size_t)(r0+tid)*512 + t] : ov;
      }
      xs[tid] = xv;
    }
    // ---- layer 0 (scalar-x, XM=2) ----
    run_unit<4,2,0>(B0, HB(0,(t+3)&3), nullptr, c0, HB(0,t&3), biases + 3*4096,
                    nullptr, nullptr, 0, xs, w0c, nullptr, nullptr, 0,
                    lds_red, r0, j0, w, lane, tid);
    ++ep; grpbar(bar, ep, mh, jb, tid, (ep % 3u) == 1u);
    // ---- layer 1 ----
    run_unit<8,0,0>(B1, HB(0,t&3), HB(1,(t+3)&3), c1, HB(1,t&3), biases + 4*4096,
                    nullptr, nullptr, 0, nullptr, nullptr, nullptr, nullptr, 0,
                    lds_red, r0, j0, w, lane, tid);
    ++ep; grpbar(bar, ep, mh, jb, tid, (ep % 3u) == 1u);
    // ---- layer 2 (+ Wu partials, PM=1) ----  (this barrier carries the inv)
    run_unit<8,0,1>(B2, HB(1,t&3), HB(2,(t+3)&3), c2, HB(2,t&3), biases + 5*4096,
                    nullptr, nullptr, 0, nullptr, nullptr, Wu, partial, jb,
                    lds_red, r0, j0, w, lane, tid);
    ++ep; grpbar(bar, ep, mh, jb, tid, (ep % 3u) == 1u);
  }

  // ---- epilogue: out(510) -> dout[:,511] ----
  if (jb == 0 && tid < 64) {
    float ov = bu_p[0];
    for (int jj = 0; jj < 128; ++jj) ov += partial[jj*128 + r0 + tid];
    st_f32(dout + (size_t)(r0+tid)*512 + 511, ov);
  }
}

// ---------- host ----------
extern "C" void kernel_launch(void* const* d_in, const int* in_sizes, int n_in,
                              void* d_out, int out_size, void* d_ws, size_t ws_size,
                              hipStream_t stream)
{
  const float* x     = (const float*)d_in[0];
  const float* y     = (const float*)d_in[1];
  const int*   force = (const int*)  d_in[2];
  const float* eWih0 = (const float*)d_in[3];
  const float* eWhh0 = (const float*)d_in[4];
  const float* ebih0 = (const float*)d_in[5];
  const float* ebhh0 = (const float*)d_in[6];
  const float* eWih  = (const float*)d_in[7];
  const float* eWhh  = (const float*)d_in[8];
  const float* ebih  = (const float*)d_in[9];
  const float* ebhh  = (const float*)d_in[10];
  const float* dWih0 = (const float*)d_in[11];
  const float* dWhh0 = (const float*)d_in[12];
  const float* dbih0 = (const float*)d_in[13];
  const float* dbhh0 = (const float*)d_in[14];
  const float* dWih  = (const float*)d_in[15];
  const float* dWhh  = (const float*)d_in[16];
  const float* dbih  = (const float*)d_in[17];
  const float* dbhh  = (const float*)d_in[18];
  const float* Wu    = (const float*)d_in[19];
  const float* bu    = (const float*)d_in[20];
  float* out = (float*)d_out;

  char* ws = (char*)d_ws;
  size_t off = 0;
  auto alloc = [&](size_t bytes)->void* {
    void* pp = ws + off; off += (bytes + 255) & ~(size_t)255; return pp;
  };
  f16* Bp_e0 = (f16*)alloc(4096ULL*1024*2);
  f16* Bp_e1 = (f16*)alloc(4096ULL*2048*2);
  f16* Bp_e2 = (f16*)alloc(4096ULL*2048*2);
  f16* Bp_d0 = (f16*)alloc(4096ULL*1024*2);
  f16* Bp_d1 = (f16*)alloc(4096ULL*2048*2);
  f16* Bp_d2 = (f16*)alloc(4096ULL*2048*2);
  float* biases = (float*)alloc(6ULL*4096*4);
  f16* x16  = (f16*)alloc(128ULL*512*32*2);
  f16* W0p  = (f16*)alloc(1024ULL*128*2);
  f16* hbuf = (f16*)alloc(3ULL*4*HSZ*2);      // 3 layers x 4 ring slots
  float* partialb = (float*)alloc(128ULL*128*4);
  unsigned* bar = (unsigned*)alloc(32*1024);   // flags + epoch stripes
  (void)ws_size; (void)in_sizes; (void)n_in; (void)out_size;

  const int THR = 256;
  auto blocks = [&](long nel){ return dim3((unsigned)((nel + THR - 1)/THR)); };

  // --- prep: weight permutes ---
  long tot4 = 128L*8*2*4*64, tot8 = 128L*8*2*8*64;
  hipLaunchKernelGGL(permB, blocks(tot4), dim3(THR), 0, stream,
                     eWhh0, 1024, eWhh0, 1024, Bp_e0, 4, tot4);
  hipLaunchKernelGGL(permB, blocks(tot8), dim3(THR), 0, stream,
                     eWih, 1024, eWhh, 1024, Bp_e1, 8, tot8);
  hipLaunchKernelGGL(permB, blocks(tot8), dim3(THR), 0, stream,
                     eWih + 4096L*1024, 1024, eWhh + 4096L*1024, 1024, Bp_e2, 8, tot8);
  hipLaunchKernelGGL(permB, blocks(tot4), dim3(THR), 0, stream,
                     dWhh0, 1024, dWhh0, 1024, Bp_d0, 4, tot4);
  hipLaunchKernelGGL(permB, blocks(tot8), dim3(THR), 0, stream,
                     dWih, 1024, dWhh, 1024, Bp_d1, 8, tot8);
  hipLaunchKernelGGL(permB, blocks(tot8), dim3(THR), 0, stream,
                     dWih + 4096L*1024, 1024, dWhh + 4096L*1024, 1024, Bp_d2, 8, tot8);
  hipLaunchKernelGGL(permW0, blocks(1024L*128), dim3(THR), 0, stream, eWih0, W0p);

  hipLaunchKernelGGL(addvec, blocks(4096), dim3(THR), 0, stream, ebih0, ebhh0, biases + 0*4096, 4096);
  hipLaunchKernelGGL(addvec, blocks(4096), dim3(THR), 0, stream, ebih, ebhh, biases + 1*4096, 4096);
  hipLaunchKernelGGL(addvec, blocks(4096), dim3(THR), 0, stream, ebih + 4096, ebhh + 4096, biases + 2*4096, 4096);
  hipLaunchKernelGGL(addvec, blocks(4096), dim3(THR), 0, stream, dbih0, dbhh0, biases + 3*4096, 4096);
  hipLaunchKernelGGL(addvec, blocks(4096), dim3(THR), 0, stream, dbih, dbhh, biases + 4*4096, 4096);
  hipLaunchKernelGGL(addvec, blocks(4096), dim3(THR), 0, stream, dbih + 4096, dbhh + 4096, biases + 5*4096, 4096);

  hipLaunchKernelGGL(cvtf16, blocks(128L*512*32), dim3(THR), 0, stream, x, x16, 128L*512*32);
  hipLaunchKernelGGL(zero_hc, blocks(3L*4*HSZ), dim3(THR), 0, stream, hbuf, bar);

  // --- persistent cooperative kernel: encoder + decoder ---
  void* kargs[] = {
    (void*)&Bp_e0, (void*)&Bp_e1, (void*)&Bp_e2,
    (void*)&Bp_d0, (void*)&Bp_d1, (void*)&Bp_d2,
    (void*)&biases, (void*)&x16, (void*)&W0p,
    (void*)&dWih0, (void*)&Wu, (void*)&bu,
    (void*)&y, (void*)&force,
    (void*)&hbuf, (void*)&partialb, (void*)&out,
    (void*)&bar
  };
  hipLaunchCooperativeKernel((const void*)persist, dim3(256), dim3(512), kargs, 0, stream);
}